// Round 5
// baseline (114.739 us; speedup 1.0000x reference)
//
#include <hip/hip_runtime.h>
#include <math.h>

// k1 (seg_starts): starts[r] = first sample index of ray r, starts[N] = M.
//     int4-vectorized coalesced pass over ray_id.
// k2 (voxel_march): one wave per ray, 8 samples/lane => 512-sample capacity.
//     Ray lengths are Binomial(M,1/N) (mean 256, sigma 16), so every ray in
//     this dataset fits in ONE iteration: all 8 vector loads issue together
//     (no inter-chunk serial chain), one 6-step shuffle ladder per ray.
//     Loop retained for correctness on lengths > 512.
//     Branchless edges: address-clamped loads; invalid samples get density
//     -1e30 -> om=1, alpha=0, weight=0.
//
// Math: om = exp(-0.5*softplus(x)) = rsqrt(1+exp(x)); alpha = 1-om.
// out[r] = sum w_i * sigmoid(rgb_i) + alphainv_last  (white background).

__device__ __forceinline__ float sigm(float x) {
    return __builtin_amdgcn_rcpf(1.0f + __expf(-x));
}

__global__ __launch_bounds__(256) void seg_starts_kernel(
    const int* __restrict__ ray_id, int* __restrict__ starts, int M, int N)
{
    const int i4 = (blockIdx.x * 256 + threadIdx.x) * 4;
    if (i4 >= M) return;

    if (i4 + 3 < M) {
        const int4 v = *(const int4*)(ray_id + i4);
        const int prev = (i4 == 0) ? -1 : ray_id[i4 - 1];
        for (int r = prev + 1; r <= v.x; ++r) starts[r] = i4 + 0;
        for (int r = v.x + 1; r <= v.y; ++r) starts[r] = i4 + 1;
        for (int r = v.y + 1; r <= v.z; ++r) starts[r] = i4 + 2;
        for (int r = v.z + 1; r <= v.w; ++r) starts[r] = i4 + 3;
        if (i4 + 4 == M) {
            for (int r = v.w + 1; r <= N; ++r) starts[r] = M;  // tail + sentinel
        }
    } else {
        int prev = (i4 == 0) ? -1 : ray_id[i4 - 1];
        for (int k = 0; k < 4 && i4 + k < M; ++k) {
            const int cur = ray_id[i4 + k];
            for (int r = prev + 1; r <= cur; ++r) starts[r] = i4 + k;
            prev = cur;
            if (i4 + k == M - 1)
                for (int r = cur + 1; r <= N; ++r) starts[r] = M;
        }
    }
}

__global__ __launch_bounds__(256) void voxel_march_kernel(
    const float* __restrict__ density,
    const float* __restrict__ rgb_raw,
    const float* __restrict__ shift,
    const int*   __restrict__ starts,
    float* __restrict__ out,
    int M, int N)
{
    const int lane = threadIdx.x & 63;
    const int wave = threadIdx.x >> 6;
    const int ray  = blockIdx.x * 4 + wave;
    if (ray >= N) return;

    const float sh = shift[0];
    const int begin = starts[ray];
    const int end   = starts[ray + 1];

    float carry = 1.0f;
    float acc0 = 0.0f, acc1 = 0.0f, acc2 = 0.0f;

    for (int base = (begin & ~7); base < end; base += 512) {
        const int b8 = base + 8 * lane;          // this lane's 8 logical samples
        const int ba = min(b8, M - 8);           // address-safe clamp

        // all loads issue together: 2x dwordx4 density + 6x dwordx4 rgb
        const float4 dd0 = *(const float4*)(density + ba);
        const float4 dd1 = *(const float4*)(density + ba + 4);
        const float4* rp = (const float4*)(rgb_raw + 3 * ba);
        float r[24];
        {
            const float4 q0 = rp[0], q1 = rp[1], q2 = rp[2];
            const float4 q3 = rp[3], q4 = rp[4], q5 = rp[5];
            r[0]=q0.x;  r[1]=q0.y;  r[2]=q0.z;  r[3]=q0.w;
            r[4]=q1.x;  r[5]=q1.y;  r[6]=q1.z;  r[7]=q1.w;
            r[8]=q2.x;  r[9]=q2.y;  r[10]=q2.z; r[11]=q2.w;
            r[12]=q3.x; r[13]=q3.y; r[14]=q3.z; r[15]=q3.w;
            r[16]=q4.x; r[17]=q4.y; r[18]=q4.z; r[19]=q4.w;
            r[20]=q5.x; r[21]=q5.y; r[22]=q5.z; r[23]=q5.w;
        }
        float d[8] = {dd0.x, dd0.y, dd0.z, dd0.w, dd1.x, dd1.y, dd1.z, dd1.w};

        // validity mask; invalid -> density -1e30 -> om=1, alpha=0
        float om[8], al[8];
        #pragma unroll
        for (int k = 0; k < 8; ++k) {
            const int j = b8 + k;
            const bool v = (j >= begin) & (j < end);
            const float x = (v ? d[k] : -1e30f) + sh;
            om[k] = __builtin_amdgcn_rsqf(1.0f + __expf(x));
            al[k] = 1.0f - om[k];
        }

        // lane product (tree), then wave-wide inclusive cumprod over lanes
        float p = ((om[0]*om[1])*(om[2]*om[3])) * ((om[4]*om[5])*(om[6]*om[7]));
        #pragma unroll
        for (int off = 1; off < 64; off <<= 1) {
            float q = __shfl_up(p, off, 64);
            if (lane >= off) p *= q;
        }
        float excl = __shfl_up(p, 1, 64);
        if (lane == 0) excl = 1.0f;

        // per-sample transmittance chain within the lane
        float t = carry * excl;
        #pragma unroll
        for (int k = 0; k < 8; ++k) {
            const float w = al[k] * t;
            acc0 += w * sigm(r[3*k+0]);
            acc1 += w * sigm(r[3*k+1]);
            acc2 += w * sigm(r[3*k+2]);
            t *= om[k];
        }

        carry *= __shfl(p, 63, 64);
    }

    // wave reduction
    #pragma unroll
    for (int off = 32; off > 0; off >>= 1) {
        acc0 += __shfl_down(acc0, off, 64);
        acc1 += __shfl_down(acc1, off, 64);
        acc2 += __shfl_down(acc2, off, 64);
    }

    if (lane == 0) {
        out[3 * ray + 0] = acc0 + carry;   // + alphainv_last
        out[3 * ray + 1] = acc1 + carry;
        out[3 * ray + 2] = acc2 + carry;
    }
}

extern "C" void kernel_launch(void* const* d_in, const int* in_sizes, int n_in,
                              void* d_out, int out_size, void* d_ws, size_t ws_size,
                              hipStream_t stream)
{
    const float* density = (const float*)d_in[0];
    const float* rgb_raw = (const float*)d_in[1];
    const float* shift   = (const float*)d_in[2];
    const int*   ray_id  = (const int*)d_in[3];
    float* out = (float*)d_out;

    const int M = in_sizes[0];
    const int N = out_size / 3;

    int* starts = (int*)d_ws;
    const int t1 = (M + 3) / 4;
    seg_starts_kernel<<<(t1 + 255) / 256, 256, 0, stream>>>(ray_id, starts, M, N);

    const int rays_per_block = 4;
    const int blocks = (N + rays_per_block - 1) / rays_per_block;
    voxel_march_kernel<<<blocks, 256, 0, stream>>>(density, rgb_raw, shift,
                                                   starts, out, M, N);
}